// Round 1
// baseline (924.554 us; speedup 1.0000x reference)
//
#include <hip/hip_runtime.h>

// MessagePassing: out[dst[e], :] += w[e] * x[src[e], :]
// N=100000 nodes, E=1000000 edges, F=64 features, fp32.
// Inputs: d_in[0]=x [N*F] f32, d_in[1]=edge_weight [E] f32,
//         d_in[2]=edge_index [2*E] int (row0=src, row1=dst), d_in[3]=num_nodes [1] int.
// Output: d_out [N*F] f32. Harness poisons d_out with 0xAA -> we zero it first.

#define FDIM 64

__global__ void __launch_bounds__(256)
scatter_edges_kernel(const float* __restrict__ x,
                     const float* __restrict__ w,
                     const int* __restrict__ src,
                     const int* __restrict__ dst,
                     float* __restrict__ out,
                     int E) {
    int gid = blockIdx.x * blockDim.x + threadIdx.x;
    int e = gid >> 4;        // 16 lanes per edge
    int q = gid & 15;        // float4 chunk index within the 64-float row
    if (e >= E) return;

    int s = src[e];
    int d = dst[e];
    float we = w[e];

    const float4* xrow = reinterpret_cast<const float4*>(x + (size_t)s * FDIM);
    float4 v = xrow[q];

    float* o = out + (size_t)d * FDIM + q * 4;
    atomicAdd(o + 0, we * v.x);
    atomicAdd(o + 1, we * v.y);
    atomicAdd(o + 2, we * v.z);
    atomicAdd(o + 3, we * v.w);
}

extern "C" void kernel_launch(void* const* d_in, const int* in_sizes, int n_in,
                              void* d_out, int out_size, void* d_ws, size_t ws_size,
                              hipStream_t stream) {
    const float* x  = (const float*)d_in[0];
    const float* w  = (const float*)d_in[1];
    const int* eidx = (const int*)d_in[2];
    int E = in_sizes[1];              // edge_weight has E elements
    const int* src = eidx;            // edge_index[0, :]
    const int* dst = eidx + E;        // edge_index[1, :]
    float* out = (float*)d_out;

    // zero the poisoned output (graph-capture-safe: becomes a memset node)
    hipMemsetAsync(out, 0, (size_t)out_size * sizeof(float), stream);

    int threads_total = E * 16;
    int block = 256;
    int grid = (threads_total + block - 1) / block;
    scatter_edges_kernel<<<grid, block, 0, stream>>>(x, w, src, dst, out, E);
}

// Round 2
// 448.707 us; speedup vs baseline: 2.0605x; 2.0605x over previous
//
#include <hip/hip_runtime.h>

// MessagePassing: out[dst[e], :] += w[e] * x[src[e], :]
// N=100000, E=1000000, F=64, fp32.
// Strategy: counting-sort edges by dst (hist -> scan -> scatter records),
// then one segment-reduce gather per node. No fp32 atomics on out, writes
// are fully coalesced, x gather reads served by L2/L3.

#define FDIM 64

// ---------------- fallback (ws too small): round-1 atomic kernel ----------
__global__ void __launch_bounds__(256)
scatter_edges_kernel(const float* __restrict__ x,
                     const float* __restrict__ w,
                     const int* __restrict__ src,
                     const int* __restrict__ dst,
                     float* __restrict__ out,
                     int E) {
    int gid = blockIdx.x * blockDim.x + threadIdx.x;
    int e = gid >> 4;
    int q = gid & 15;
    if (e >= E) return;
    int s = src[e];
    int d = dst[e];
    float we = w[e];
    const float4* xrow = reinterpret_cast<const float4*>(x + (size_t)s * FDIM);
    float4 v = xrow[q];
    float* o = out + (size_t)d * FDIM + q * 4;
    atomicAdd(o + 0, we * v.x);
    atomicAdd(o + 1, we * v.y);
    atomicAdd(o + 2, we * v.z);
    atomicAdd(o + 3, we * v.w);
}

// ---------------- sorted path ----------------
__global__ void __launch_bounds__(256)
hist_kernel(const int* __restrict__ dst, int* __restrict__ deg, int E) {
    int e = blockIdx.x * 256 + threadIdx.x;
    if (e < E) atomicAdd(&deg[dst[e]], 1);
}

__global__ void __launch_bounds__(1024)
scan_kernel(const int* __restrict__ deg, int* __restrict__ off,
            int* __restrict__ cursor, int N, int E) {
    __shared__ int part[1024];
    int tid = threadIdx.x;
    int chunk = (N + 1023) >> 10;
    int start = tid * chunk;
    int end = start + chunk; if (end > N) end = N;
    int sum = 0;
    if (start < N) for (int i = start; i < end; ++i) sum += deg[i];
    part[tid] = sum;
    __syncthreads();
    // Hillis-Steele inclusive scan over 1024 partials
    for (int s = 1; s < 1024; s <<= 1) {
        int t = (tid >= s) ? part[tid - s] : 0;
        __syncthreads();
        part[tid] += t;
        __syncthreads();
    }
    int run = (tid == 0) ? 0 : part[tid - 1];
    if (start < N) {
        for (int i = start; i < end; ++i) {
            off[i] = run;
            cursor[i] = run;
            run += deg[i];
        }
    }
    if (tid == 0) off[N] = E;
}

__global__ void __launch_bounds__(256)
scatter_sort_kernel(const int* __restrict__ src, const int* __restrict__ dst,
                    const float* __restrict__ w, int* __restrict__ cursor,
                    int2* __restrict__ rec, int E) {
    int e = blockIdx.x * 256 + threadIdx.x;
    if (e >= E) return;
    int d = dst[e];
    int p = atomicAdd(&cursor[d], 1);
    int2 r;
    r.x = src[e];
    r.y = __float_as_int(w[e]);
    rec[p] = r;
}

__global__ void __launch_bounds__(256)
gather_kernel(const float* __restrict__ x, const int2* __restrict__ rec,
              const int* __restrict__ off, float* __restrict__ out, int N) {
    int gid = blockIdx.x * 256 + threadIdx.x;
    int node = gid >> 4;
    int q = gid & 15;
    if (node >= N) return;
    int beg = off[node];
    int end = off[node + 1];
    float4 acc = {0.f, 0.f, 0.f, 0.f};
    for (int i = beg; i < end; ++i) {
        int2 r = rec[i];                      // 16 lanes same addr -> broadcast
        float wv = __int_as_float(r.y);
        float4 v = reinterpret_cast<const float4*>(x + (size_t)r.x * FDIM)[q];
        acc.x += wv * v.x;
        acc.y += wv * v.y;
        acc.z += wv * v.z;
        acc.w += wv * v.w;
    }
    reinterpret_cast<float4*>(out + (size_t)node * FDIM)[q] = acc;
}

extern "C" void kernel_launch(void* const* d_in, const int* in_sizes, int n_in,
                              void* d_out, int out_size, void* d_ws, size_t ws_size,
                              hipStream_t stream) {
    const float* x  = (const float*)d_in[0];
    const float* w  = (const float*)d_in[1];
    const int* eidx = (const int*)d_in[2];
    int E = in_sizes[1];
    int N = out_size / FDIM;
    const int* src = eidx;
    const int* dst = eidx + E;
    float* out = (float*)d_out;

    // workspace layout
    int*  deg    = (int*)d_ws;            // N
    int*  off    = deg + N;               // N+1
    int*  cursor = off + N + 1;           // N
    size_t rec_off = (((size_t)(3 * N + 1)) * sizeof(int) + 7) & ~(size_t)7;
    int2* rec = (int2*)((char*)d_ws + rec_off);  // E records, 8 B each
    size_t need = rec_off + (size_t)E * sizeof(int2);

    if (ws_size < need) {
        // fallback: atomic scatter (round-1 kernel)
        hipMemsetAsync(out, 0, (size_t)out_size * sizeof(float), stream);
        int threads_total = E * 16;
        int grid = (threads_total + 255) / 256;
        scatter_edges_kernel<<<grid, 256, 0, stream>>>(x, w, src, dst, out, E);
        return;
    }

    hipMemsetAsync(deg, 0, (size_t)N * sizeof(int), stream);

    int gridE = (E + 255) / 256;
    hist_kernel<<<gridE, 256, 0, stream>>>(dst, deg, E);
    scan_kernel<<<1, 1024, 0, stream>>>(deg, off, cursor, N, E);
    scatter_sort_kernel<<<gridE, 256, 0, stream>>>(src, dst, w, cursor, rec, E);

    int threads_total = N * 16;
    int gridN = (threads_total + 255) / 256;
    gather_kernel<<<gridN, 256, 0, stream>>>(x, rec, off, out, N);
}

// Round 3
// 239.841 us; speedup vs baseline: 3.8549x; 1.8709x over previous
//
#include <hip/hip_runtime.h>

// MessagePassing: out[dst[e], :] += w[e] * x[src[e], :]
// N=100000, E=1000000, F=64, fp32.
// Counting-sort edges by dst (hist -> hierarchical scan -> scatter records),
// then one segment-reduce gather per node. No fp32 atomics on out.

#define FDIM 64

// ---------------- fallback (ws too small): atomic kernel ----------
__global__ void __launch_bounds__(256)
scatter_edges_kernel(const float* __restrict__ x,
                     const float* __restrict__ w,
                     const int* __restrict__ src,
                     const int* __restrict__ dst,
                     float* __restrict__ out,
                     int E) {
    int gid = blockIdx.x * blockDim.x + threadIdx.x;
    int e = gid >> 4;
    int q = gid & 15;
    if (e >= E) return;
    int s = src[e];
    int d = dst[e];
    float we = w[e];
    const float4* xrow = reinterpret_cast<const float4*>(x + (size_t)s * FDIM);
    float4 v = xrow[q];
    float* o = out + (size_t)d * FDIM + q * 4;
    atomicAdd(o + 0, we * v.x);
    atomicAdd(o + 1, we * v.y);
    atomicAdd(o + 2, we * v.z);
    atomicAdd(o + 3, we * v.w);
}

// ---------------- sorted path ----------------
__global__ void __launch_bounds__(256)
hist_kernel(const int* __restrict__ dst, int* __restrict__ deg, int E) {
    int e = blockIdx.x * 256 + threadIdx.x;
    if (e < E) atomicAdd(&deg[dst[e]], 1);
}

// Hierarchical scan: pass1 computes per-thread (4 elem) sums + block totals.
__global__ void __launch_bounds__(256)
scan_pass1(const int* __restrict__ deg, int* __restrict__ tpre,
           int* __restrict__ bsum, int N) {
    int b = blockIdx.x, t = threadIdx.x;
    int base = b * 1024 + t * 4;
    int v0 = 0, v1 = 0, v2 = 0, v3 = 0;
    if (base + 3 < N) {
        int4 v = *reinterpret_cast<const int4*>(deg + base);
        v0 = v.x; v1 = v.y; v2 = v.z; v3 = v.w;
    } else {
        if (base + 0 < N) v0 = deg[base + 0];
        if (base + 1 < N) v1 = deg[base + 1];
        if (base + 2 < N) v2 = deg[base + 2];
    }
    int s = v0 + v1 + v2 + v3;
    __shared__ int sh[256];
    sh[t] = s;
    __syncthreads();
    for (int d = 1; d < 256; d <<= 1) {
        int u = (t >= d) ? sh[t - d] : 0;
        __syncthreads();
        sh[t] += u;
        __syncthreads();
    }
    tpre[b * 256 + t] = sh[t] - s;      // exclusive prefix within block
    if (t == 255) bsum[b] = sh[255];
}

__global__ void __launch_bounds__(256)
scan_pass2(const int* __restrict__ bsum, int* __restrict__ boff, int nb) {
    int t = threadIdx.x;
    __shared__ int sh[256];
    int v = (t < nb) ? bsum[t] : 0;
    sh[t] = v;
    __syncthreads();
    for (int d = 1; d < 256; d <<= 1) {
        int u = (t >= d) ? sh[t - d] : 0;
        __syncthreads();
        sh[t] += u;
        __syncthreads();
    }
    if (t < nb) boff[t] = sh[t] - v;    // exclusive block offsets
}

__global__ void __launch_bounds__(256)
scan_pass3(const int* __restrict__ deg, const int* __restrict__ tpre,
           const int* __restrict__ boff, int* __restrict__ off,
           int* __restrict__ cursor, int N, int E) {
    int b = blockIdx.x, t = threadIdx.x;
    int base = b * 1024 + t * 4;
    int run = boff[b] + tpre[b * 256 + t];
    #pragma unroll
    for (int k = 0; k < 4; ++k) {
        int i = base + k;
        if (i < N) {
            off[i] = run;
            cursor[i] = run;
            run += deg[i];
        }
    }
    if (b == 0 && t == 0) off[N] = E;
}

// single-block scan fallback (only if nb > 256, i.e. N > 262144)
__global__ void __launch_bounds__(1024)
scan_kernel(const int* __restrict__ deg, int* __restrict__ off,
            int* __restrict__ cursor, int N, int E) {
    __shared__ int part[1024];
    int tid = threadIdx.x;
    int chunk = (N + 1023) >> 10;
    int start = tid * chunk;
    int end = start + chunk; if (end > N) end = N;
    int sum = 0;
    if (start < N) for (int i = start; i < end; ++i) sum += deg[i];
    part[tid] = sum;
    __syncthreads();
    for (int s = 1; s < 1024; s <<= 1) {
        int t = (tid >= s) ? part[tid - s] : 0;
        __syncthreads();
        part[tid] += t;
        __syncthreads();
    }
    int run = (tid == 0) ? 0 : part[tid - 1];
    if (start < N) {
        for (int i = start; i < end; ++i) {
            off[i] = run;
            cursor[i] = run;
            run += deg[i];
        }
    }
    if (tid == 0) off[N] = E;
}

__global__ void __launch_bounds__(256)
scatter_sort_kernel(const int* __restrict__ src, const int* __restrict__ dst,
                    const float* __restrict__ w, int* __restrict__ cursor,
                    int2* __restrict__ rec, int E) {
    int e = blockIdx.x * 256 + threadIdx.x;
    if (e >= E) return;
    int d = dst[e];
    int p = atomicAdd(&cursor[d], 1);
    int2 r;
    r.x = src[e];
    r.y = __float_as_int(w[e]);
    rec[p] = r;
}

__global__ void __launch_bounds__(256)
gather_kernel(const float* __restrict__ x, const int2* __restrict__ rec,
              const int* __restrict__ off, float* __restrict__ out, int N) {
    int gid = blockIdx.x * 256 + threadIdx.x;
    int node = gid >> 4;
    int q = gid & 15;
    if (node >= N) return;
    int beg = off[node];
    int end = off[node + 1];
    float4 acc = {0.f, 0.f, 0.f, 0.f};
    for (int i = beg; i < end; ++i) {
        int2 r = rec[i];                      // 16 lanes same addr -> broadcast
        float wv = __int_as_float(r.y);
        float4 v = reinterpret_cast<const float4*>(x + (size_t)r.x * FDIM)[q];
        acc.x += wv * v.x;
        acc.y += wv * v.y;
        acc.z += wv * v.z;
        acc.w += wv * v.w;
    }
    reinterpret_cast<float4*>(out + (size_t)node * FDIM)[q] = acc;
}

extern "C" void kernel_launch(void* const* d_in, const int* in_sizes, int n_in,
                              void* d_out, int out_size, void* d_ws, size_t ws_size,
                              hipStream_t stream) {
    const float* x  = (const float*)d_in[0];
    const float* w  = (const float*)d_in[1];
    const int* eidx = (const int*)d_in[2];
    int E = in_sizes[1];
    int N = out_size / FDIM;
    const int* src = eidx;
    const int* dst = eidx + E;
    float* out = (float*)d_out;

    int nb = (N + 1023) / 1024;   // scan blocks (1024 elems each)

    // workspace layout
    int*  deg    = (int*)d_ws;                 // N
    int*  off    = deg + N;                    // N+1
    int*  cursor = off + N + 1;                // N
    int*  tpre   = cursor + N;                 // nb*256
    int*  bsum   = tpre + (size_t)nb * 256;    // nb
    int*  boff   = bsum + nb;                  // nb
    size_t ints = (size_t)(3 * N + 1) + (size_t)nb * 258;
    size_t rec_off = (ints * sizeof(int) + 7) & ~(size_t)7;
    int2* rec = (int2*)((char*)d_ws + rec_off);  // E records
    size_t need = rec_off + (size_t)E * sizeof(int2);

    if (ws_size < need) {
        hipMemsetAsync(out, 0, (size_t)out_size * sizeof(float), stream);
        int grid = (E * 16 + 255) / 256;
        scatter_edges_kernel<<<grid, 256, 0, stream>>>(x, w, src, dst, out, E);
        return;
    }

    hipMemsetAsync(deg, 0, (size_t)N * sizeof(int), stream);

    int gridE = (E + 255) / 256;
    hist_kernel<<<gridE, 256, 0, stream>>>(dst, deg, E);

    if (nb <= 256) {
        scan_pass1<<<nb, 256, 0, stream>>>(deg, tpre, bsum, N);
        scan_pass2<<<1, 256, 0, stream>>>(bsum, boff, nb);
        scan_pass3<<<nb, 256, 0, stream>>>(deg, tpre, boff, off, cursor, N, E);
    } else {
        scan_kernel<<<1, 1024, 0, stream>>>(deg, off, cursor, N, E);
    }

    scatter_sort_kernel<<<gridE, 256, 0, stream>>>(src, dst, w, cursor, rec, E);

    int gridN = (N * 16 + 255) / 256;
    gather_kernel<<<gridN, 256, 0, stream>>>(x, rec, off, out, N);
}